// Round 1
// 424.120 us; speedup vs baseline: 1.0154x; 1.0154x over previous
//
#include <hip/hip_runtime.h>

// CKKS-style polynomial softmax over rows of 2048 fp32.
// x: [16, 2048, 2048]. One WAVE (64 lanes) per row; 32 elems/lane (8 x float4).
// No LDS, no __syncthreads: the row-sum is a pure wave-level shfl_xor butterfly,
// so every wave is independent and loads/stores pipeline freely across waves.

typedef float v4f __attribute__((ext_vector_type(4)));

#define ROWLEN 2048
#define TPB    256
#define ROWS_PER_BLOCK 4   // 4 waves/block, one row each

__global__ __launch_bounds__(TPB) void ckks_softmax_kernel(
    const float* __restrict__ x,
    const float* __restrict__ exp_c,   // 9 coeffs, power basis
    const float* __restrict__ inv_c,   // 5 coeffs
    const int*   __restrict__ iters_p, // single int (==3)
    float* __restrict__ out)
{
    const int lane = threadIdx.x & 63;
    const int wave = threadIdx.x >> 6;
    const int row  = blockIdx.x * ROWS_PER_BLOCK + wave;
    const size_t base = (size_t)row * ROWLEN;

    const v4f* __restrict__ xv = (const v4f*)(x + base);
    v4f*       __restrict__ ov = (v4f*)(out + base);

    // Uniform coefficient loads -> SGPRs.
    const float c0 = exp_c[0], c1 = exp_c[1], c2 = exp_c[2], c3 = exp_c[3],
                c4 = exp_c[4], c5 = exp_c[5], c6 = exp_c[6], c7 = exp_c[7],
                c8 = exp_c[8];
    const float i0 = inv_c[0], i1 = inv_c[1], i2 = inv_c[2], i3 = inv_c[3],
                i4 = inv_c[4];
    const int iters = *iters_p;

    // Issue all 8 row loads up front: 8 x global_load_dwordx4 in flight per lane.
    // Each wave instruction covers 64 lanes x 16B = 1 KB contiguous. Streaming
    // data (never re-read) -> nontemporal.
    v4f v[8];
    #pragma unroll
    for (int k = 0; k < 8; ++k)
        v[k] = __builtin_nontemporal_load(&xv[lane + 64 * k]);

    auto horner8 = [&](float t) -> float {
        float acc = c8;
        acc = fmaf(acc, t, c7);
        acc = fmaf(acc, t, c6);
        acc = fmaf(acc, t, c5);
        acc = fmaf(acc, t, c4);
        acc = fmaf(acc, t, c3);
        acc = fmaf(acc, t, c2);
        acc = fmaf(acc, t, c1);
        acc = fmaf(acc, t, c0);
        return acc;
    };

    // e = poly_exp(x), component-wise partial sums (keeps a shallow sum tree).
    v4f acc4 = {0.0f, 0.0f, 0.0f, 0.0f};
    #pragma unroll
    for (int k = 0; k < 8; ++k) {
        v4f e;
        e.x = horner8(v[k].x);
        e.y = horner8(v[k].y);
        e.z = horner8(v[k].z);
        e.w = horner8(v[k].w);
        v[k] = e;            // keep row's e-values resident in VGPRs
        acc4 += e;
    }
    float s = (acc4.x + acc4.y) + (acc4.z + acc4.w);

    // In-wave butterfly reduction: every lane ends with the full row sum.
    #pragma unroll
    for (int off = 32; off > 0; off >>= 1)
        s += __shfl_xor(s, off, 64);

    // Initial reciprocal guess (degree-4 Horner), redundant per lane (cheap).
    float y = i4;
    y = fmaf(y, s, i3);
    y = fmaf(y, s, i2);
    y = fmaf(y, s, i1);
    y = fmaf(y, s, i0);

    // Newton-Raphson: y <- y * (2 - s*y); iteration count read from device.
    for (int i = 0; i < iters; ++i)
        y = y * (2.0f - s * y);

    // Scale and stream out.
    #pragma unroll
    for (int k = 0; k < 8; ++k) {
        v4f e = v[k] * y;
        __builtin_nontemporal_store(e, &ov[lane + 64 * k]);
    }
}

extern "C" void kernel_launch(void* const* d_in, const int* in_sizes, int n_in,
                              void* d_out, int out_size, void* d_ws, size_t ws_size,
                              hipStream_t stream) {
    const float* x     = (const float*)d_in[0];
    const float* exp_c = (const float*)d_in[1];
    const float* inv_c = (const float*)d_in[2];
    const int*   iters = (const int*)d_in[3];
    float* out = (float*)d_out;

    const int n_rows = out_size / ROWLEN;            // 16 * 2048 = 32768
    const int n_blocks = n_rows / ROWS_PER_BLOCK;    // 8192
    ckks_softmax_kernel<<<n_blocks, TPB, 0, stream>>>(x, exp_c, inv_c, iters, out);
}